// Round 5
// baseline (521.458 us; speedup 1.0000x reference)
//
#include <hip/hip_runtime.h>

typedef __attribute__((ext_vector_type(8))) short shortx8;
typedef __attribute__((ext_vector_type(4))) float floatx4;
typedef unsigned short u16;
typedef unsigned int u32;

__device__ __forceinline__ float bf2f(unsigned short u) {
    union { unsigned int i; float f; } v; v.i = ((unsigned int)u) << 16; return v.f;
}
__device__ __forceinline__ float bfl(u32 u) {
    union { u32 i; float f; } v; v.i = u << 16; return v.f;
}
__device__ __forceinline__ float bfh(u32 u) {
    union { u32 i; float f; } v; v.i = u & 0xFFFF0000u; return v.f;
}
__device__ __forceinline__ unsigned short f2bf(float f) {
    union { float f; unsigned int i; } v; v.f = f;
    unsigned int x = v.i;
    unsigned int r = x + 0x7FFFu + ((x >> 16) & 1u);
    return (unsigned short)(r >> 16);
}
__device__ __forceinline__ float ldf(const void* p, int i, bool f32) {
    return f32 ? ((const float*)p)[i] : bf2f(((const u16*)p)[i]);
}

// ---------------------------------------------------------------------------
// Block 0: storage-format detection (flags[0]: floats fp32; flags[1]: idx
// int64). Blocks 1..: zero the degree array.
// ---------------------------------------------------------------------------
__global__ __launch_bounds__(256) void detect_zero_k(
    const u16* __restrict__ nf, const int* __restrict__ ei,
    int* __restrict__ flags, int* __restrict__ deg, int M)
{
    int tid = threadIdx.x;
    if (blockIdx.x != 0) {
        int i = (blockIdx.x - 1) * 256 + tid;
        if (i < M) deg[i] = 0;
        return;
    }
    __shared__ int cnt[2];
    if (tid < 2) cnt[tid] = 0;
    __syncthreads();
    int c0 = 0;
    for (int i = tid; i < 65536; i += 256) {
        u16 v = nf[i];
        if ((v & 0x7F80u) == 0x7F80u) c0++;
    }
    int c1 = 0;
    for (int i = tid; i < 4096; i += 256) {
        if (ei[2 * i + 1] != 0) c1++;
    }
    atomicAdd(&cnt[0], c0);
    atomicAdd(&cnt[1], c1);
    __syncthreads();
    if (tid == 0) {
        flags[0] = (cnt[0] > 8) ? 1 : 0;
        flags[1] = (cnt[1] < 100) ? 1 : 0;
    }
}

// ---------------------------------------------------------------------------
// Prep: W -> MFMA B-fragment order (bf16); biases/We/be -> fp32 workspace.
// ---------------------------------------------------------------------------
__global__ __launch_bounds__(256) void prep_k(
    const void* __restrict__ W0, const void* __restrict__ W1,
    const void* __restrict__ W2, const void* __restrict__ W3,
    const void* __restrict__ b0, const void* __restrict__ b1,
    const void* __restrict__ b2, const void* __restrict__ b3,
    const void* __restrict__ We, const void* __restrict__ be,
    const int* __restrict__ flags,
    u16* __restrict__ WT, float* __restrict__ biasWs,
    float* __restrict__ WeWs, float* __restrict__ beWs)
{
    bool f32 = flags[0] != 0;
    int tid = threadIdx.x;
    if (blockIdx.x < 32) {
        int t = blockIdx.x * 256 + tid;
        int mat  = t >> 11;
        int r    = t & 2047;
        int lane = r & 63;
        int ks   = (r >> 6) & 3;
        int ct   = r >> 8;
        const void* W = (mat == 0) ? W0 : (mat == 1) ? W1 : (mat == 2) ? W2 : W3;
        int k0  = ks * 32 + (lane >> 4) * 8;
        int col = ct * 16 + (lane & 15);
        u16 tmp[8];
#pragma unroll
        for (int j = 0; j < 8; ++j) {
            int off = (k0 + j) * 128 + col;
            tmp[j] = f32 ? f2bf(((const float*)W)[off]) : ((const u16*)W)[off];
        }
        *(shortx8*)(WT + (size_t)t * 8) = *(const shortx8*)tmp;
    } else {
        if (tid < 128) {
            biasWs[0 * 128 + tid] = ldf(b0, tid, f32);
            biasWs[1 * 128 + tid] = ldf(b1, tid, f32);
            biasWs[2 * 128 + tid] = ldf(b2, tid, f32);
            biasWs[3 * 128 + tid] = ldf(b3, tid, f32);
        }
        WeWs[tid] = ldf(We, tid, f32);
        if (tid < 8) beWs[tid] = ldf(be, tid, f32);
    }
}

// ---------------------------------------------------------------------------
// Pass 1 over edges: rank[e] = running index of e within its target's list.
// The atomic return value IS the CSR slot — scatter pass needs no atomics.
// ---------------------------------------------------------------------------
__global__ __launch_bounds__(256) void hist_rank_k(
    const int* __restrict__ ei, int* __restrict__ deg, int* __restrict__ rank,
    int E, const int* __restrict__ flags)
{
    int e = blockIdx.x * 256 + threadIdx.x;
    if (e >= E) return;
    int tgt = flags[1] ? ei[2 * (E + e)] : ei[E + e];
    rank[e] = atomicAdd(&deg[tgt], 1);
}

// ---------------------------------------------------------------------------
// Single-block scan: deg[0..M) -> rowptr[0..M] (exclusive prefix).
// 1024 threads; per-thread chunk sum -> LDS scan -> per-chunk write-back.
// ---------------------------------------------------------------------------
__global__ __launch_bounds__(1024) void scan_all_k(
    const int* __restrict__ deg, int* __restrict__ rowptr, int M)
{
    __shared__ int s[1024];
    int tid = threadIdx.x;
    int C = (M + 1023) >> 10;
    int b0 = tid * C;
    int b1 = b0 + C; if (b1 > M) b1 = M;
    int sum = 0;
    for (int i = b0; i < b1; ++i) sum += deg[i];
    s[tid] = sum;
    __syncthreads();
#pragma unroll
    for (int off = 1; off < 1024; off <<= 1) {
        int t = (tid >= off) ? s[tid - off] : 0;
        __syncthreads();
        s[tid] += t;
        __syncthreads();
    }
    int run = s[tid] - sum;                 // exclusive offset of this chunk
    for (int i = b0; i < b1; ++i) { rowptr[i] = run; run += deg[i]; }
    if (b0 < M && b1 == M) rowptr[M] = run; // unique last nonempty chunk
}

// ---------------------------------------------------------------------------
// Fused QKV GEMM: A fragments loaded once, 3 weight matrices applied.
// ---------------------------------------------------------------------------
__global__ __launch_bounds__(256) void qkv_gemm_k(
    const void* __restrict__ A, int M,
    const u16* __restrict__ WT, const float* __restrict__ biasWs,
    u16* __restrict__ Qb, u16* __restrict__ Kb, u16* __restrict__ Vb,
    const int* __restrict__ flags)
{
    bool aF32 = flags[0] != 0;
    int lane = threadIdx.x & 63;
    int wave = threadIdx.x >> 6;
    int quad = lane >> 4;
    int l15  = lane & 15;
    int m0   = blockIdx.x * 128 + wave * 32;

    shortx8 afrag[2][4];
#pragma unroll
    for (int mt = 0; mt < 2; ++mt) {
        int row = m0 + mt * 16 + l15;
        row = row < M ? row : M - 1;
#pragma unroll
        for (int ks = 0; ks < 4; ++ks) {
            size_t base = (size_t)row * 128 + ks * 32 + quad * 8;
            if (aF32) {
                const floatx4* ap = (const floatx4*)((const float*)A + base);
                floatx4 f0 = ap[0], f1 = ap[1];
                u16 tmp[8];
#pragma unroll
                for (int j = 0; j < 4; ++j) { tmp[j] = f2bf(f0[j]); tmp[4 + j] = f2bf(f1[j]); }
                afrag[mt][ks] = *(const shortx8*)tmp;
            } else {
                afrag[mt][ks] = *(const shortx8*)((const u16*)A + base);
            }
        }
    }

    u16* outs[3] = {Qb, Kb, Vb};
#pragma unroll
    for (int mat = 0; mat < 3; ++mat) {
        floatx4 acc[2][8];
#pragma unroll
        for (int a = 0; a < 2; ++a)
#pragma unroll
            for (int b = 0; b < 8; ++b)
                acc[a][b] = (floatx4){0.f, 0.f, 0.f, 0.f};
#pragma unroll
        for (int ks = 0; ks < 4; ++ks) {
#pragma unroll
            for (int ct = 0; ct < 8; ++ct) {
                shortx8 bfrag = *(const shortx8*)(WT + (size_t)mat * 16384 +
                                                  ((size_t)(ct * 4 + ks) * 64 + lane) * 8);
                acc[0][ct] = __builtin_amdgcn_mfma_f32_16x16x32_bf16(afrag[0][ks], bfrag, acc[0][ct], 0, 0, 0);
                acc[1][ct] = __builtin_amdgcn_mfma_f32_16x16x32_bf16(afrag[1][ks], bfrag, acc[1][ct], 0, 0, 0);
            }
        }
        u16* out = outs[mat];
#pragma unroll
        for (int ct = 0; ct < 8; ++ct) {
            int col = ct * 16 + l15;
            float bs = biasWs[mat * 128 + col];
#pragma unroll
            for (int mt = 0; mt < 2; ++mt) {
#pragma unroll
                for (int r = 0; r < 4; ++r) {
                    int row = m0 + mt * 16 + quad * 4 + r;
                    if (row < M)
                        out[(size_t)row * 128 + col] = f2bf(acc[mt][ct][r] + bs);
                }
            }
        }
    }
}

// ---------------------------------------------------------------------------
// Pass 2 over edges (no atomics): pos = rowptr[tgt] + rank[e];
// perm[pos] = src; EBp[pos][h] = ef[e]·We[:,h] + be[h]  (CSR order!)
// ---------------------------------------------------------------------------
__global__ __launch_bounds__(256) void edge_scatter_k(
    const int* __restrict__ ei, const void* __restrict__ ef,
    const int* __restrict__ rank, const int* __restrict__ rowptr,
    const float* __restrict__ WeWs, const float* __restrict__ beWs,
    int* __restrict__ perm, float* __restrict__ EBp,
    int E, const int* __restrict__ flags)
{
    __shared__ float sWe[256];
    __shared__ float sbe[8];
    int tid = threadIdx.x;
    sWe[tid] = WeWs[tid];
    if (tid < 8) sbe[tid] = beWs[tid];
    __syncthreads();

    int e = blockIdx.x * 256 + tid;
    if (e >= E) return;
    bool f32 = flags[0] != 0;
    bool i64 = flags[1] != 0;

    int src = i64 ? ei[2 * e]       : ei[e];
    int tgt = i64 ? ei[2 * (E + e)] : ei[E + e];
    int pos = rowptr[tgt] + rank[e];
    perm[pos] = src;

    float v[32];
    if (f32) {
        const floatx4* ep = (const floatx4*)((const float*)ef + (size_t)e * 32);
#pragma unroll
        for (int g = 0; g < 8; ++g) {
            floatx4 t = ep[g];
#pragma unroll
            for (int j = 0; j < 4; ++j) v[g * 4 + j] = t[j];
        }
    } else {
        const shortx8* ep = (const shortx8*)((const u16*)ef + (size_t)e * 32);
#pragma unroll
        for (int g = 0; g < 4; ++g) {
            shortx8 t = ep[g];
#pragma unroll
            for (int j = 0; j < 8; ++j) v[g * 8 + j] = bf2f((unsigned short)t[j]);
        }
    }
    float eb[8];
#pragma unroll
    for (int h = 0; h < 8; ++h) eb[h] = sbe[h];
#pragma unroll
    for (int k = 0; k < 32; ++k)
#pragma unroll
        for (int h = 0; h < 8; ++h) eb[h] += v[k] * sWe[k * 8 + h];

    floatx4* op = (floatx4*)(EBp + (size_t)pos * 8);
    op[0] = (floatx4){eb[0], eb[1], eb[2], eb[3]};
    op[1] = (floatx4){eb[4], eb[5], eb[6], eb[7]};
}

// ---------------------------------------------------------------------------
// Per-node aggregation v3: one wave per node, 4 edges in flight, perm
// prefetched into registers (src via shfl, not a dependent load), EB reads
// sequential in CSR order. Zero atomics, zero LDS.
// ---------------------------------------------------------------------------
__global__ __launch_bounds__(256) void node_agg_k(
    const int* __restrict__ perm, const int* __restrict__ rowptr,
    const u16* __restrict__ Qb, const u16* __restrict__ Kb, const u16* __restrict__ Vb,
    const float* __restrict__ EBp, u16* __restrict__ aggN, int M, int E)
{
    int wave = threadIdx.x >> 6;
    int lane = threadIdx.x & 63;
    int n = blockIdx.x * 4 + wave;
    if (n >= M) return;
    int g = lane >> 4;
    int w = lane & 15;
    int h = w >> 1;

    int beg = rowptr[n], end = rowptr[n + 1];
    int pidx = beg + lane;
    if (pidx >= E) pidx = E - 1;
    int pv = perm[pidx];                       // prefetch up to 64 entries

    uint4 qw = ((const uint4*)(Qb + (size_t)n * 128))[w];
    float q0 = bfl(qw.x), q1 = bfh(qw.x), q2 = bfl(qw.y), q3 = bfh(qw.y);
    float q4 = bfl(qw.z), q5 = bfh(qw.z), q6 = bfl(qw.w), q7 = bfh(qw.w);

    float acc[8];
#pragma unroll
    for (int j = 0; j < 8; ++j) acc[j] = 0.f;
    float dsum = 0.f;

    for (int i = beg; i < end; i += 4) {
        int idx = i + g;
        bool valid = idx < end;
        int cidx = valid ? idx : (end - 1);
        int off = cidx - beg;
        int src = (off < 64) ? __shfl(pv, off) : perm[cidx];
        float eb = EBp[(size_t)cidx * 8 + h];
        uint4 kw = ((const uint4*)(Kb + (size_t)src * 128))[w];
        uint4 vw = ((const uint4*)(Vb + (size_t)src * 128))[w];
        float part = q0 * bfl(kw.x) + q1 * bfh(kw.x)
                   + q2 * bfl(kw.y) + q3 * bfh(kw.y)
                   + q4 * bfl(kw.z) + q5 * bfh(kw.z)
                   + q6 * bfl(kw.w) + q7 * bfh(kw.w);
        part += __shfl_xor(part, 1);
        float p = valid ? __expf(part * 0.25f + eb) : 0.f;
        dsum += p;
        acc[0] += p * bfl(vw.x); acc[1] += p * bfh(vw.x);
        acc[2] += p * bfl(vw.y); acc[3] += p * bfh(vw.y);
        acc[4] += p * bfl(vw.z); acc[5] += p * bfh(vw.z);
        acc[6] += p * bfl(vw.w); acc[7] += p * bfh(vw.w);
    }

    dsum += __shfl_xor(dsum, 16);
    dsum += __shfl_xor(dsum, 32);
#pragma unroll
    for (int j = 0; j < 8; ++j) {
        acc[j] += __shfl_xor(acc[j], 16);
        acc[j] += __shfl_xor(acc[j], 32);
    }
    if (g == 0) {
        float inv = 1.0f / (dsum + 1e-10f);
        uint4 o;
        o.x = (u32)f2bf(acc[0] * inv) | ((u32)f2bf(acc[1] * inv) << 16);
        o.y = (u32)f2bf(acc[2] * inv) | ((u32)f2bf(acc[3] * inv) << 16);
        o.z = (u32)f2bf(acc[4] * inv) | ((u32)f2bf(acc[5] * inv) << 16);
        o.w = (u32)f2bf(acc[6] * inv) | ((u32)f2bf(acc[7] * inv) << 16);
        ((uint4*)(aggN + (size_t)n * 128))[w] = o;
    }
}

// ---------------------------------------------------------------------------
// Output GEMM: C = aggN(bf16) @ Wo + bo, out fp32/bf16 per flags[0].
// ---------------------------------------------------------------------------
__global__ __launch_bounds__(256) void out_gemm_k(
    const u16* __restrict__ A, int M,
    const u16* __restrict__ WT, const float* __restrict__ bias,
    void* __restrict__ out, const int* __restrict__ flags)
{
    bool oF32 = flags[0] != 0;
    int lane = threadIdx.x & 63;
    int wave = threadIdx.x >> 6;
    int quad = lane >> 4;
    int l15  = lane & 15;
    int m0   = blockIdx.x * 128 + wave * 32;

    floatx4 acc[2][8];
#pragma unroll
    for (int a = 0; a < 2; ++a)
#pragma unroll
        for (int b = 0; b < 8; ++b)
            acc[a][b] = (floatx4){0.f, 0.f, 0.f, 0.f};

#pragma unroll
    for (int ks = 0; ks < 4; ++ks) {
        shortx8 afrag[2];
#pragma unroll
        for (int mt = 0; mt < 2; ++mt) {
            int row = m0 + mt * 16 + l15;
            row = row < M ? row : M - 1;
            afrag[mt] = *(const shortx8*)(A + (size_t)row * 128 + ks * 32 + quad * 8);
        }
#pragma unroll
        for (int ct = 0; ct < 8; ++ct) {
            shortx8 bfrag = *(const shortx8*)(WT + ((size_t)(ct * 4 + ks) * 64 + lane) * 8);
            acc[0][ct] = __builtin_amdgcn_mfma_f32_16x16x32_bf16(afrag[0], bfrag, acc[0][ct], 0, 0, 0);
            acc[1][ct] = __builtin_amdgcn_mfma_f32_16x16x32_bf16(afrag[1], bfrag, acc[1][ct], 0, 0, 0);
        }
    }

#pragma unroll
    for (int ct = 0; ct < 8; ++ct) {
        int col = ct * 16 + l15;
        float bs = bias[col];
#pragma unroll
        for (int mt = 0; mt < 2; ++mt) {
#pragma unroll
            for (int r = 0; r < 4; ++r) {
                int row = m0 + mt * 16 + quad * 4 + r;
                if (row < M) {
                    float v = acc[mt][ct][r] + bs;
                    if (oF32) ((float*)out)[(size_t)row * 128 + col] = v;
                    else      ((u16*)out)[(size_t)row * 128 + col] = f2bf(v);
                }
            }
        }
    }
}

extern "C" void kernel_launch(void* const* d_in, const int* in_sizes, int n_in,
                              void* d_out, int out_size, void* d_ws, size_t ws_size,
                              hipStream_t stream)
{
    const void* nf = d_in[0];
    const int*  ei = (const int*)d_in[1];
    const void* ef = d_in[2];
    const void* Wq = d_in[3];  const void* bq = d_in[4];
    const void* Wk = d_in[5];  const void* bk = d_in[6];
    const void* Wv = d_in[7];  const void* bv = d_in[8];
    const void* We = d_in[9];  const void* be = d_in[10];
    const void* Wo = d_in[11]; const void* bo = d_in[12];

    int M = in_sizes[0] / 128;   // 50000
    int E = in_sizes[1] / 2;     // 800000
    int nb = (M + 255) / 256;

    // ---- workspace layout ----
    char* ws = (char*)d_ws;
    int*   flags  = (int*)(ws + 0);
    float* biasWs = (float*)(ws + 256);
    float* WeWs   = (float*)(ws + 2304);
    float* beWs   = (float*)(ws + 3328);
    u16*   WT     = (u16*)(ws + 4096);                  // 131072 B
    size_t O1 = 4096 + 131072;
    size_t qkv = (size_t)M * 128 * 2;
    u16* Qb = (u16*)(ws + O1);
    u16* Kb = (u16*)(ws + O1 + qkv);
    u16* Vb = (u16*)(ws + O1 + 2 * qkv);
    size_t O2 = O1 + 3 * qkv;
    float* EBp = (float*)(ws + O2);                     // E*8 fp32, CSR order
    size_t O3 = O2 + (size_t)E * 8 * 4;
    int* perm   = (int*)(ws + O3);                      // E
    int* rank   = perm + E;                             // E
    int* deg    = rank + E;                             // M
    int* rowptr = deg + M;                              // M+1
    u16* aggN   = Qb;   // safe alias: wave n reads Qb[n] before writing aggN[n]

    detect_zero_k<<<1 + nb, 256, 0, stream>>>((const u16*)nf, ei, flags, deg, M);
    prep_k<<<33, 256, 0, stream>>>(Wq, Wk, Wv, Wo, bq, bk, bv, bo, We, be,
                                   flags, WT, biasWs, WeWs, beWs);

    int eblocks = (E + 255) / 256;
    hist_rank_k<<<eblocks, 256, 0, stream>>>(ei, deg, rank, E, flags);
    scan_all_k<<<1, 1024, 0, stream>>>(deg, rowptr, M);

    int gblocks = (M + 127) / 128;
    qkv_gemm_k<<<gblocks, 256, 0, stream>>>(nf, M, WT, biasWs, Qb, Kb, Vb, flags);

    edge_scatter_k<<<eblocks, 256, 0, stream>>>(ei, ef, rank, rowptr, WeWs, beWs,
                                                perm, EBp, E, flags);

    node_agg_k<<<(M + 3) / 4, 256, 0, stream>>>(perm, rowptr, Qb, Kb, Vb, EBp, aggN, M, E);

    out_gemm_k<<<gblocks, 256, 0, stream>>>(aggN, M, WT + 3 * 16384, biasWs + 384, d_out, flags);
}

// Round 6
// 453.064 us; speedup vs baseline: 1.1510x; 1.1510x over previous
//
#include <hip/hip_runtime.h>

typedef __attribute__((ext_vector_type(8))) short shortx8;
typedef __attribute__((ext_vector_type(4))) float floatx4;
typedef unsigned short u16;
typedef unsigned int u32;

__device__ __forceinline__ float bf2f(unsigned short u) {
    union { unsigned int i; float f; } v; v.i = ((unsigned int)u) << 16; return v.f;
}
__device__ __forceinline__ float bfl(u32 u) {
    union { u32 i; float f; } v; v.i = u << 16; return v.f;
}
__device__ __forceinline__ float bfh(u32 u) {
    union { u32 i; float f; } v; v.i = u & 0xFFFF0000u; return v.f;
}
__device__ __forceinline__ unsigned short f2bf(float f) {
    union { float f; unsigned int i; } v; v.f = f;
    unsigned int x = v.i;
    unsigned int r = x + 0x7FFFu + ((x >> 16) & 1u);
    return (unsigned short)(r >> 16);
}
__device__ __forceinline__ float ldf(const void* p, int i, bool f32) {
    return f32 ? ((const float*)p)[i] : bf2f(((const u16*)p)[i]);
}

// ---------------------------------------------------------------------------
// Block 0: storage-format detection (flags[0]: floats fp32; flags[1]: idx
// int64). Blocks 1..: zero the degree array.
// ---------------------------------------------------------------------------
__global__ __launch_bounds__(256) void detect_zero_k(
    const u16* __restrict__ nf, const int* __restrict__ ei,
    int* __restrict__ flags, int* __restrict__ deg, int M)
{
    int tid = threadIdx.x;
    if (blockIdx.x != 0) {
        int i = (blockIdx.x - 1) * 256 + tid;
        if (i < M) deg[i] = 0;
        return;
    }
    __shared__ int cnt[2];
    if (tid < 2) cnt[tid] = 0;
    __syncthreads();
    int c0 = 0;
    for (int i = tid; i < 65536; i += 256) {
        u16 v = nf[i];
        if ((v & 0x7F80u) == 0x7F80u) c0++;
    }
    int c1 = 0;
    for (int i = tid; i < 4096; i += 256) {
        if (ei[2 * i + 1] != 0) c1++;
    }
    atomicAdd(&cnt[0], c0);
    atomicAdd(&cnt[1], c1);
    __syncthreads();
    if (tid == 0) {
        flags[0] = (cnt[0] > 8) ? 1 : 0;
        flags[1] = (cnt[1] < 100) ? 1 : 0;
    }
}

// ---------------------------------------------------------------------------
// Prep: W -> MFMA B-fragment order (bf16); biases/We/be -> fp32 workspace.
// ---------------------------------------------------------------------------
__global__ __launch_bounds__(256) void prep_k(
    const void* __restrict__ W0, const void* __restrict__ W1,
    const void* __restrict__ W2, const void* __restrict__ W3,
    const void* __restrict__ b0, const void* __restrict__ b1,
    const void* __restrict__ b2, const void* __restrict__ b3,
    const void* __restrict__ We, const void* __restrict__ be,
    const int* __restrict__ flags,
    u16* __restrict__ WT, float* __restrict__ biasWs,
    float* __restrict__ WeWs, float* __restrict__ beWs)
{
    bool f32 = flags[0] != 0;
    int tid = threadIdx.x;
    if (blockIdx.x < 32) {
        int t = blockIdx.x * 256 + tid;
        int mat  = t >> 11;
        int r    = t & 2047;
        int lane = r & 63;
        int ks   = (r >> 6) & 3;
        int ct   = r >> 8;
        const void* W = (mat == 0) ? W0 : (mat == 1) ? W1 : (mat == 2) ? W2 : W3;
        int k0  = ks * 32 + (lane >> 4) * 8;
        int col = ct * 16 + (lane & 15);
        u16 tmp[8];
#pragma unroll
        for (int j = 0; j < 8; ++j) {
            int off = (k0 + j) * 128 + col;
            tmp[j] = f32 ? f2bf(((const float*)W)[off]) : ((const u16*)W)[off];
        }
        *(shortx8*)(WT + (size_t)t * 8) = *(const shortx8*)tmp;
    } else {
        if (tid < 128) {
            biasWs[0 * 128 + tid] = ldf(b0, tid, f32);
            biasWs[1 * 128 + tid] = ldf(b1, tid, f32);
            biasWs[2 * 128 + tid] = ldf(b2, tid, f32);
            biasWs[3 * 128 + tid] = ldf(b3, tid, f32);
        }
        WeWs[tid] = ldf(We, tid, f32);
        if (tid < 8) beWs[tid] = ldf(be, tid, f32);
    }
}

// ---------------------------------------------------------------------------
// Pass 1 over edges: rank[e] = running index of e within its target's list.
// The atomic return value IS the CSR slot — scatter pass needs no atomics.
// ---------------------------------------------------------------------------
__global__ __launch_bounds__(256) void hist_rank_k(
    const int* __restrict__ ei, int* __restrict__ deg, int* __restrict__ rank,
    int E, const int* __restrict__ flags)
{
    int e = blockIdx.x * 256 + threadIdx.x;
    if (e >= E) return;
    int tgt = flags[1] ? ei[2 * (E + e)] : ei[E + e];
    rank[e] = atomicAdd(&deg[tgt], 1);
}

// ---------------------------------------------------------------------------
// Parallel scan (3 tiny kernels): deg -> rowptr (exclusive).
// scan1: per-block inclusive scan; scan2: block-sum exclusive scan;
// scan3: rowptr[i+1] = incl[i] + boff[block(i)], rowptr[0] = 0.
// ---------------------------------------------------------------------------
__global__ __launch_bounds__(256) void scan1_k(
    const int* __restrict__ deg, int* __restrict__ incl, int* __restrict__ bsum, int M)
{
    __shared__ int s[256];
    int tid = threadIdx.x;
    int i = blockIdx.x * 256 + tid;
    int v = (i < M) ? deg[i] : 0;
    s[tid] = v;
    __syncthreads();
#pragma unroll
    for (int off = 1; off < 256; off <<= 1) {
        int t = (tid >= off) ? s[tid - off] : 0;
        __syncthreads();
        s[tid] += t;
        __syncthreads();
    }
    if (i < M) incl[i] = s[tid];
    if (tid == 255) bsum[blockIdx.x] = s[255];
}

__global__ __launch_bounds__(256) void scan2_k(
    const int* __restrict__ bsum, int* __restrict__ boff, int nb)
{
    __shared__ int s[256];
    int tid = threadIdx.x;
    int v = (tid < nb) ? bsum[tid] : 0;
    s[tid] = v;
    __syncthreads();
#pragma unroll
    for (int off = 1; off < 256; off <<= 1) {
        int t = (tid >= off) ? s[tid - off] : 0;
        __syncthreads();
        s[tid] += t;
        __syncthreads();
    }
    if (tid < nb) boff[tid] = s[tid] - v;   // exclusive
}

__global__ __launch_bounds__(256) void scan3_k(
    const int* __restrict__ incl, const int* __restrict__ boff,
    int* __restrict__ rowptr, int M)
{
    int i = blockIdx.x * 256 + threadIdx.x;
    if (i >= M) return;
    rowptr[i + 1] = incl[i] + boff[i >> 8];
    if (i == 0) rowptr[0] = 0;
}

// ---------------------------------------------------------------------------
// Fused QKV GEMM: A fragments loaded once, 3 weight matrices applied.
// ---------------------------------------------------------------------------
__global__ __launch_bounds__(256) void qkv_gemm_k(
    const void* __restrict__ A, int M,
    const u16* __restrict__ WT, const float* __restrict__ biasWs,
    u16* __restrict__ Qb, u16* __restrict__ Kb, u16* __restrict__ Vb,
    const int* __restrict__ flags)
{
    bool aF32 = flags[0] != 0;
    int lane = threadIdx.x & 63;
    int wave = threadIdx.x >> 6;
    int quad = lane >> 4;
    int l15  = lane & 15;
    int m0   = blockIdx.x * 128 + wave * 32;

    shortx8 afrag[2][4];
#pragma unroll
    for (int mt = 0; mt < 2; ++mt) {
        int row = m0 + mt * 16 + l15;
        row = row < M ? row : M - 1;
#pragma unroll
        for (int ks = 0; ks < 4; ++ks) {
            size_t base = (size_t)row * 128 + ks * 32 + quad * 8;
            if (aF32) {
                const floatx4* ap = (const floatx4*)((const float*)A + base);
                floatx4 f0 = ap[0], f1 = ap[1];
                u16 tmp[8];
#pragma unroll
                for (int j = 0; j < 4; ++j) { tmp[j] = f2bf(f0[j]); tmp[4 + j] = f2bf(f1[j]); }
                afrag[mt][ks] = *(const shortx8*)tmp;
            } else {
                afrag[mt][ks] = *(const shortx8*)((const u16*)A + base);
            }
        }
    }

    u16* outs[3] = {Qb, Kb, Vb};
#pragma unroll
    for (int mat = 0; mat < 3; ++mat) {
        floatx4 acc[2][8];
#pragma unroll
        for (int a = 0; a < 2; ++a)
#pragma unroll
            for (int b = 0; b < 8; ++b)
                acc[a][b] = (floatx4){0.f, 0.f, 0.f, 0.f};
#pragma unroll
        for (int ks = 0; ks < 4; ++ks) {
#pragma unroll
            for (int ct = 0; ct < 8; ++ct) {
                shortx8 bfrag = *(const shortx8*)(WT + (size_t)mat * 16384 +
                                                  ((size_t)(ct * 4 + ks) * 64 + lane) * 8);
                acc[0][ct] = __builtin_amdgcn_mfma_f32_16x16x32_bf16(afrag[0][ks], bfrag, acc[0][ct], 0, 0, 0);
                acc[1][ct] = __builtin_amdgcn_mfma_f32_16x16x32_bf16(afrag[1][ks], bfrag, acc[1][ct], 0, 0, 0);
            }
        }
        u16* out = outs[mat];
#pragma unroll
        for (int ct = 0; ct < 8; ++ct) {
            int col = ct * 16 + l15;
            float bs = biasWs[mat * 128 + col];
#pragma unroll
            for (int mt = 0; mt < 2; ++mt) {
#pragma unroll
                for (int r = 0; r < 4; ++r) {
                    int row = m0 + mt * 16 + quad * 4 + r;
                    if (row < M)
                        out[(size_t)row * 128 + col] = f2bf(acc[mt][ct][r] + bs);
                }
            }
        }
    }
}

// ---------------------------------------------------------------------------
// Pass 2 over edges (no atomics): pos = rowptr[tgt] + rank[e];
// perm[pos] = src; EBp[pos][h] = ef[e]·We[:,h] + be[h]  (CSR order!)
// ---------------------------------------------------------------------------
__global__ __launch_bounds__(256) void edge_scatter_k(
    const int* __restrict__ ei, const void* __restrict__ ef,
    const int* __restrict__ rank, const int* __restrict__ rowptr,
    const float* __restrict__ WeWs, const float* __restrict__ beWs,
    int* __restrict__ perm, float* __restrict__ EBp,
    int E, const int* __restrict__ flags)
{
    __shared__ float sWe[256];
    __shared__ float sbe[8];
    int tid = threadIdx.x;
    sWe[tid] = WeWs[tid];
    if (tid < 8) sbe[tid] = beWs[tid];
    __syncthreads();

    int e = blockIdx.x * 256 + tid;
    if (e >= E) return;
    bool f32 = flags[0] != 0;
    bool i64 = flags[1] != 0;

    int src = i64 ? ei[2 * e]       : ei[e];
    int tgt = i64 ? ei[2 * (E + e)] : ei[E + e];
    int pos = rowptr[tgt] + rank[e];
    perm[pos] = src;

    float v[32];
    if (f32) {
        const floatx4* ep = (const floatx4*)((const float*)ef + (size_t)e * 32);
#pragma unroll
        for (int g = 0; g < 8; ++g) {
            floatx4 t = ep[g];
#pragma unroll
            for (int j = 0; j < 4; ++j) v[g * 4 + j] = t[j];
        }
    } else {
        const shortx8* ep = (const shortx8*)((const u16*)ef + (size_t)e * 32);
#pragma unroll
        for (int g = 0; g < 4; ++g) {
            shortx8 t = ep[g];
#pragma unroll
            for (int j = 0; j < 8; ++j) v[g * 8 + j] = bf2f((unsigned short)t[j]);
        }
    }
    float eb[8];
#pragma unroll
    for (int h = 0; h < 8; ++h) eb[h] = sbe[h];
#pragma unroll
    for (int k = 0; k < 32; ++k)
#pragma unroll
        for (int h = 0; h < 8; ++h) eb[h] += v[k] * sWe[k * 8 + h];

    floatx4* op = (floatx4*)(EBp + (size_t)pos * 8);
    op[0] = (floatx4){eb[0], eb[1], eb[2], eb[3]};
    op[1] = (floatx4){eb[4], eb[5], eb[6], eb[7]};
}

// ---------------------------------------------------------------------------
// Per-node aggregation: one wave per node, 4 edges in flight, perm
// prefetched into registers (src via shfl), EB reads sequential (CSR order).
// Zero atomics, zero LDS.
// ---------------------------------------------------------------------------
__global__ __launch_bounds__(256) void node_agg_k(
    const int* __restrict__ perm, const int* __restrict__ rowptr,
    const u16* __restrict__ Qb, const u16* __restrict__ Kb, const u16* __restrict__ Vb,
    const float* __restrict__ EBp, u16* __restrict__ aggN, int M, int E)
{
    int wave = threadIdx.x >> 6;
    int lane = threadIdx.x & 63;
    int n = blockIdx.x * 4 + wave;
    if (n >= M) return;
    int g = lane >> 4;
    int w = lane & 15;
    int h = w >> 1;

    int beg = rowptr[n], end = rowptr[n + 1];
    int pidx = beg + lane;
    if (pidx >= E) pidx = E - 1;
    int pv = perm[pidx];                       // prefetch up to 64 entries

    uint4 qw = ((const uint4*)(Qb + (size_t)n * 128))[w];
    float q0 = bfl(qw.x), q1 = bfh(qw.x), q2 = bfl(qw.y), q3 = bfh(qw.y);
    float q4 = bfl(qw.z), q5 = bfh(qw.z), q6 = bfl(qw.w), q7 = bfh(qw.w);

    float acc[8];
#pragma unroll
    for (int j = 0; j < 8; ++j) acc[j] = 0.f;
    float dsum = 0.f;

    for (int i = beg; i < end; i += 4) {
        int idx = i + g;
        bool valid = idx < end;
        int cidx = valid ? idx : (end - 1);
        int off = cidx - beg;
        int src = (off < 64) ? __shfl(pv, off) : perm[cidx];
        float eb = EBp[(size_t)cidx * 8 + h];
        uint4 kw = ((const uint4*)(Kb + (size_t)src * 128))[w];
        uint4 vw = ((const uint4*)(Vb + (size_t)src * 128))[w];
        float part = q0 * bfl(kw.x) + q1 * bfh(kw.x)
                   + q2 * bfl(kw.y) + q3 * bfh(kw.y)
                   + q4 * bfl(kw.z) + q5 * bfh(kw.z)
                   + q6 * bfl(kw.w) + q7 * bfh(kw.w);
        part += __shfl_xor(part, 1);
        float p = valid ? __expf(part * 0.25f + eb) : 0.f;
        dsum += p;
        acc[0] += p * bfl(vw.x); acc[1] += p * bfh(vw.x);
        acc[2] += p * bfl(vw.y); acc[3] += p * bfh(vw.y);
        acc[4] += p * bfl(vw.z); acc[5] += p * bfh(vw.z);
        acc[6] += p * bfl(vw.w); acc[7] += p * bfh(vw.w);
    }

    dsum += __shfl_xor(dsum, 16);
    dsum += __shfl_xor(dsum, 32);
#pragma unroll
    for (int j = 0; j < 8; ++j) {
        acc[j] += __shfl_xor(acc[j], 16);
        acc[j] += __shfl_xor(acc[j], 32);
    }
    if (g == 0) {
        float inv = 1.0f / (dsum + 1e-10f);
        uint4 o;
        o.x = (u32)f2bf(acc[0] * inv) | ((u32)f2bf(acc[1] * inv) << 16);
        o.y = (u32)f2bf(acc[2] * inv) | ((u32)f2bf(acc[3] * inv) << 16);
        o.z = (u32)f2bf(acc[4] * inv) | ((u32)f2bf(acc[5] * inv) << 16);
        o.w = (u32)f2bf(acc[6] * inv) | ((u32)f2bf(acc[7] * inv) << 16);
        ((uint4*)(aggN + (size_t)n * 128))[w] = o;
    }
}

// ---------------------------------------------------------------------------
// Output GEMM: C = aggN(bf16) @ Wo + bo, out fp32/bf16 per flags[0].
// ---------------------------------------------------------------------------
__global__ __launch_bounds__(256) void out_gemm_k(
    const u16* __restrict__ A, int M,
    const u16* __restrict__ WT, const float* __restrict__ bias,
    void* __restrict__ out, const int* __restrict__ flags)
{
    bool oF32 = flags[0] != 0;
    int lane = threadIdx.x & 63;
    int wave = threadIdx.x >> 6;
    int quad = lane >> 4;
    int l15  = lane & 15;
    int m0   = blockIdx.x * 128 + wave * 32;

    floatx4 acc[2][8];
#pragma unroll
    for (int a = 0; a < 2; ++a)
#pragma unroll
        for (int b = 0; b < 8; ++b)
            acc[a][b] = (floatx4){0.f, 0.f, 0.f, 0.f};

#pragma unroll
    for (int ks = 0; ks < 4; ++ks) {
        shortx8 afrag[2];
#pragma unroll
        for (int mt = 0; mt < 2; ++mt) {
            int row = m0 + mt * 16 + l15;
            row = row < M ? row : M - 1;
            afrag[mt] = *(const shortx8*)(A + (size_t)row * 128 + ks * 32 + quad * 8);
        }
#pragma unroll
        for (int ct = 0; ct < 8; ++ct) {
            shortx8 bfrag = *(const shortx8*)(WT + ((size_t)(ct * 4 + ks) * 64 + lane) * 8);
            acc[0][ct] = __builtin_amdgcn_mfma_f32_16x16x32_bf16(afrag[0], bfrag, acc[0][ct], 0, 0, 0);
            acc[1][ct] = __builtin_amdgcn_mfma_f32_16x16x32_bf16(afrag[1], bfrag, acc[1][ct], 0, 0, 0);
        }
    }

#pragma unroll
    for (int ct = 0; ct < 8; ++ct) {
        int col = ct * 16 + l15;
        float bs = bias[col];
#pragma unroll
        for (int mt = 0; mt < 2; ++mt) {
#pragma unroll
            for (int r = 0; r < 4; ++r) {
                int row = m0 + mt * 16 + quad * 4 + r;
                if (row < M) {
                    float v = acc[mt][ct][r] + bs;
                    if (oF32) ((float*)out)[(size_t)row * 128 + col] = v;
                    else      ((u16*)out)[(size_t)row * 128 + col] = f2bf(v);
                }
            }
        }
    }
}

extern "C" void kernel_launch(void* const* d_in, const int* in_sizes, int n_in,
                              void* d_out, int out_size, void* d_ws, size_t ws_size,
                              hipStream_t stream)
{
    const void* nf = d_in[0];
    const int*  ei = (const int*)d_in[1];
    const void* ef = d_in[2];
    const void* Wq = d_in[3];  const void* bq = d_in[4];
    const void* Wk = d_in[5];  const void* bk = d_in[6];
    const void* Wv = d_in[7];  const void* bv = d_in[8];
    const void* We = d_in[9];  const void* be = d_in[10];
    const void* Wo = d_in[11]; const void* bo = d_in[12];

    int M = in_sizes[0] / 128;   // 50000
    int E = in_sizes[1] / 2;     // 800000
    int nb = (M + 255) / 256;    // 196 <= 256, fits scan2's one block

    // ---- workspace layout ----
    char* ws = (char*)d_ws;
    int*   flags  = (int*)(ws + 0);
    float* biasWs = (float*)(ws + 256);
    float* WeWs   = (float*)(ws + 2304);
    float* beWs   = (float*)(ws + 3328);
    u16*   WT     = (u16*)(ws + 4096);                  // 131072 B
    size_t O1 = 4096 + 131072;
    size_t qkv = (size_t)M * 128 * 2;
    u16* Qb = (u16*)(ws + O1);
    u16* Kb = (u16*)(ws + O1 + qkv);
    u16* Vb = (u16*)(ws + O1 + 2 * qkv);
    size_t O2 = O1 + 3 * qkv;
    float* EBp = (float*)(ws + O2);                     // E*8 fp32, CSR order
    size_t O3 = O2 + (size_t)E * 8 * 4;
    int* perm   = (int*)(ws + O3);                      // E
    int* rank   = perm + E;                             // E
    int* deg    = rank + E;                             // M
    int* incl   = deg + M;                              // M
    int* rowptr = incl + M;                             // M+1
    int* bsum   = rowptr + M + 1;                       // 256
    int* boff   = bsum + 256;                           // 256
    u16* aggN   = Qb;   // safe alias: wave n reads Qb[n] before writing aggN[n]

    detect_zero_k<<<1 + nb, 256, 0, stream>>>((const u16*)nf, ei, flags, deg, M);
    prep_k<<<33, 256, 0, stream>>>(Wq, Wk, Wv, Wo, bq, bk, bv, bo, We, be,
                                   flags, WT, biasWs, WeWs, beWs);

    int eblocks = (E + 255) / 256;
    hist_rank_k<<<eblocks, 256, 0, stream>>>(ei, deg, rank, E, flags);
    scan1_k<<<nb, 256, 0, stream>>>(deg, incl, bsum, M);
    scan2_k<<<1, 256, 0, stream>>>(bsum, boff, nb);
    scan3_k<<<nb, 256, 0, stream>>>(incl, boff, rowptr, M);

    int gblocks = (M + 127) / 128;
    qkv_gemm_k<<<gblocks, 256, 0, stream>>>(nf, M, WT, biasWs, Qb, Kb, Vb, flags);

    edge_scatter_k<<<eblocks, 256, 0, stream>>>(ei, ef, rank, rowptr, WeWs, beWs,
                                                perm, EBp, E, flags);

    node_agg_k<<<(M + 3) / 4, 256, 0, stream>>>(perm, rowptr, Qb, Kb, Vb, EBp, aggN, M, E);

    out_gemm_k<<<gblocks, 256, 0, stream>>>(aggN, M, WT + 3 * 16384, biasWs + 384, d_out, flags);
}